// Round 14
// baseline (122.681 us; speedup 1.0000x reference)
//
#include <hip/hip_runtime.h>
#include <cstdint>

#define BB 16
#define NN 25200
#define NCLS 80
#define NF (5 + NCLS)
#define MAXDET 300
#define MTGT 50
#define CONF 0.8f
#define NMSTH 0.4f
#define WORDS 10
#define NBINS 2048
#define SBUF 2048
#define CAPK 8192                           // per-batch candidate list (+53 sigma)
#define APB 64                              // anchors per chunk
#define CPB 394                             // chunks per batch: 393x64 + 48
#define SCORE_BLOCKS (BB * CPB)             // 6304
#define NTGT_BLOCKS ((BB * MTGT + 127) / 128)
#define HSTRIDE 33                          // hist LDS row stride (bank de-alias)

// workspace byte offsets
#define WS_HIST 0                                          // 16*2048*4 = 131072
#define WS_CNT  (131072)                                   // 16 counters, 64B apart
#define WS_KEYS (WS_CNT + 1024)                            // 16*8192*8 = 1 MB
#define WS_DS   (WS_KEYS + (size_t)BB * CAPK * 8)
#define WS_DI   (WS_DS + (size_t)BB * MAXDET * 4)
#define WS_GBOX (WS_DI + (size_t)BB * MAXDET * 4)
#define WS_GLAB (WS_GBOX + (size_t)BB * MAXDET * 16)

// output float offsets (return order: pb, ps, pl, pv, tb, ts, tl, tv)
#define O_PB 0
#define O_PS (BB * MAXDET * 4)
#define O_PL (O_PS + BB * MAXDET)
#define O_PV (O_PL + BB * MAXDET)
#define O_TB (O_PV + BB * MAXDET)
#define O_TS (O_TB + BB * MTGT * 4)
#define O_TL (O_TS + BB * MTGT)
#define O_TV (O_TL + BB * MTGT)

// zero per-batch histograms + counters (graph-safe, no memset)
__global__ __launch_bounds__(1024) void k_zero(int* __restrict__ ghist,
                                               int* __restrict__ cnt) {
    int i = blockIdx.x * 1024 + threadIdx.x;
    if (i < BB * NBINS) ghist[i] = 0;
    if (i < 256) cnt[i] = 0;
}

// 128-thread block stages one 64-anchor chunk (21.76 KB -> 7 blocks/CU) via
// async global_load_lds width=16. Scan: 2 threads/anchor (2-way bank = free),
// 4 max accumulators (order-independent -> bit-exact), one shfl_xor, single
// f32 mul. NEW: candidates (score>CONF) are pushed straight to the per-batch
// global key list (wave-aggregated counter atomic) + per-batch global 2048-bin
// histogram (fire-and-forget atomics) -- the scores array round-trip and
// select's full 25200-scan are gone. Blocks are gridded 394/batch so no chunk
// straddles a batch (tail chunk = 48 anchors, guarded). Tail blocks: targets.
__global__ __launch_bounds__(128) void k_score(const float* __restrict__ preds,
                                               int* __restrict__ ghist,
                                               int* __restrict__ cnt,
                                               unsigned long long* __restrict__ keys,
                                               const float* __restrict__ tt,
                                               const int* __restrict__ len,
                                               float* __restrict__ out) {
    __shared__ float st[APB * NF];          // 21760 B
    int tid = threadIdx.x;
    int bid = blockIdx.x;

    if (bid >= SCORE_BLOCKS) {              // fused target transform
        int t = (bid - SCORE_BLOCKS) * 128 + tid;
        if (t < BB * MTGT) {
            int b = t / MTGT, m = t - b * MTGT;
            const float* row = tt + (size_t)t * 6;
            bool valid = m < len[b];
            float cx = row[0], cy = row[1], w = row[2], h = row[3];
            float x1 = cx - 0.5f * w, y1 = cy - 0.5f * h;
            float* tb = out + O_TB + (size_t)t * 4;
            tb[0] = valid ? x1 : 0.f;
            tb[1] = valid ? y1 : 0.f;
            tb[2] = valid ? (x1 + w) : 0.f;
            tb[3] = valid ? (y1 + h) : 0.f;
            out[O_TS + t] = valid ? row[4] : 0.f;
            out[O_TL + t] = valid ? (float)(int)row[5] : -1.f;
            out[O_TV + t] = valid ? 1.f : 0.f;
        }
        return;
    }

    int b  = bid / CPB;                     // batch
    int cb = bid - b * CPB;                 // chunk within batch
    int count = (cb == CPB - 1) ? (NN - (CPB - 1) * APB) : APB;   // 48 or 64
    int nv4 = count * NF / 4;               // 1020 or 1360 float4

    int w = tid >> 6;                       // wave id (uniform per wave)
    const float4* src = (const float4*)(preds + ((size_t)b * NN + (size_t)cb * APB) * NF);
    #pragma unroll
    for (int i = 0; i < 11; ++i) {
        int idx = i * 128 + tid;
        if (idx < nv4) {
            __builtin_amdgcn_global_load_lds(
                (const __attribute__((address_space(1))) void*)(src + idx),
                (__attribute__((address_space(3))) void*)(st + (i * 128 + w * 64) * 4),
                16, 0, 0);
        }
    }
    __syncthreads();                        // drains vmcnt -> LDS valid

    int a = tid >> 1, h = tid & 1;          // anchor, half
    bool pass = false;
    unsigned long long key = 0ull;
    if (a < count) {
        const float* cls = st + a * NF + 5 + h * 40;
        float m0 = cls[0], m1 = cls[1], m2 = cls[2], m3 = cls[3];
        #pragma unroll
        for (int f = 4; f < 40; f += 4) {
            m0 = fmaxf(m0, cls[f]);     m1 = fmaxf(m1, cls[f + 1]);
            m2 = fmaxf(m2, cls[f + 2]); m3 = fmaxf(m3, cls[f + 3]);
        }
        float m = fmaxf(fmaxf(m0, m1), fmaxf(m2, m3));
        m = fmaxf(m, __shfl_xor(m, 1));
        if (h == 0) {
            float s = st[a * NF + 4] * m;   // single f32 mul, bit-exact vs np
            if (s > CONF) {
                pass = true;
                unsigned u = __float_as_uint(s);
                int bin = (int)((u - 0x3F400000u) >> 12);
                bin = bin < 0 ? 0 : (bin > NBINS - 1 ? NBINS - 1 : bin);
                atomicAdd(&ghist[b * NBINS + bin], 1);   // no return -> fire-and-forget
                unsigned aidx = (unsigned)(cb * APB + a);
                key = ((unsigned long long)u << 32) |
                      (unsigned long long)(0xFFFFFFFFu - aidx);
            }
        }
    }
    // wave-aggregated append: ONE atomic-return per wave on a 64B-padded counter
    int lane = tid & 63;
    unsigned long long mask = __ballot(pass);
    int wcnt = __popcll(mask);
    int bs = 0;
    if (lane == 0 && wcnt) bs = atomicAdd(&cnt[b * 16], wcnt);
    bs = __shfl(bs, 0);
    if (pass) {
        int pos = bs + __popcll(mask & ((1ull << lane) - 1ull));
        if (pos < CAPK) keys[(size_t)b * CAPK + pos] = key;
    }
}

// One block per batch, candidate-space only: hist[b] (2048 ints) -> LDS, proven
// cut-finder, filter ~4800 keys (5 iters, was a 25200-scan), proven bitonic.
// Coarse bins only SELECT (cut-bin ties all included); the exact 64-bit key
// sort ORDERS -> bit-identical to a full sort (JAX top_k tie semantics via
// inverted index; append-order nondeterminism erased by the total order).
__global__ __launch_bounds__(1024) void k_select(const int* __restrict__ ghist,
                                                 const int* __restrict__ cnt,
                                                 const unsigned long long* __restrict__ keys,
                                                 float* __restrict__ dscore,
                                                 unsigned* __restrict__ didx) {
    __shared__ int hist[64 * HSTRIDE];      // superbin-major, stride 33: bank-clean
    __shared__ unsigned long long sk[SBUF];
    __shared__ int lcnt2;
    __shared__ int scut;
    int b = blockIdx.x;
    int tid = threadIdx.x;
    int lane = tid & 63;

    if (tid == 0) lcnt2 = 0;
    for (int i = tid; i < SBUF; i += 1024) sk[i] = 0ull;   // pad keys for sort
    for (int i = tid; i < NBINS; i += 1024)                // global hist -> LDS
        hist[(i >> 5) * HSTRIDE + (i & 31)] = ghist[b * NBINS + i];
    __syncthreads();

    // phase B: find cut bin (largest bin with suffix-count >= 300), one wave
    if (tid < 64) {
        int sb = 0;
        #pragma unroll
        for (int k = 0; k < 32; ++k) sb += hist[lane * HSTRIDE + k];  // banks clean
        int cum = sb;                              // suffix sum over 64 superbins
        #pragma unroll
        for (int d = 1; d < 64; d <<= 1) {
            int o = __shfl_down(cum, d);
            if (lane + d < 64) cum += o;
        }
        unsigned long long m = __ballot(cum >= MAXDET);
        int cutbin = 0;
        if (m) {
            int cutS = 63 - __clzll(m);
            int tail = (cutS < 63) ? __shfl(cum, cutS + 1) : 0;
            int hh = (lane < 32) ? hist[cutS * HSTRIDE + lane] : 0;
            int c2 = hh;                           // suffix sum within superbin
            #pragma unroll
            for (int d = 1; d < 32; d <<= 1) {
                int o = __shfl_down(c2, d);
                if (lane + d < 32) c2 += o;
            }
            c2 += tail;
            unsigned long long m2 = __ballot(lane < 32 && c2 >= MAXDET);
            int cutL = 63 - __clzll(m2);           // m2 != 0 guaranteed
            cutbin = cutS * 32 + cutL;
        }
        if (lane == 0) scut = cutbin;
    }
    __syncthreads();
    int cutbin = scut;

    // phase C: filter candidate keys by bin >= cutbin (wave-aggregated)
    int M = cnt[b * 16]; if (M > CAPK) M = CAPK;
    for (int i = tid; i < ((M + 1023) & ~1023); i += 1024) {
        bool pass = false;
        unsigned long long key = 0ull;
        if (i < M) {
            key = keys[(size_t)b * CAPK + i];
            unsigned u = (unsigned)(key >> 32);
            int bin = (int)((u - 0x3F400000u) >> 12);
            bin = bin < 0 ? 0 : (bin > NBINS - 1 ? NBINS - 1 : bin);
            pass = bin >= cutbin;
        }
        unsigned long long mask = __ballot(pass);
        int wcnt = __popcll(mask);
        int bs = 0;
        if (lane == 0 && wcnt) bs = atomicAdd(&lcnt2, wcnt);
        bs = __shfl(bs, 0);
        if (pass) {
            int pos = bs + __popcll(mask & ((1ull << lane) - 1ull));
            if (pos < SBUF) sk[pos] = key;
        }
    }
    __syncthreads();

    // phase D: bitonic sort P in {512,1024,2048} elements, descending (proven)
    int M2 = lcnt2; if (M2 > SBUF) M2 = SBUF;
    unsigned P = 512;
    while ((int)P < M2) P <<= 1;

    for (unsigned k = 2; k <= P; k <<= 1) {
        for (unsigned j = k >> 1; j > 0; j >>= 1) {
            __syncthreads();
            for (unsigned i = tid; i < P; i += 1024) {
                unsigned ixj = i ^ j;
                if (ixj > i) {
                    unsigned long long a = sk[i], d = sk[ixj];
                    bool desc = ((i & k) == 0);
                    if (desc ? (a < d) : (a > d)) { sk[i] = d; sk[ixj] = a; }
                }
            }
        }
    }
    __syncthreads();
    for (int q = tid; q < MAXDET; q += 1024) {
        unsigned long long key = sk[q];
        unsigned sbits = (unsigned)(key >> 32);
        dscore[b * MAXDET + q] = __uint_as_float(sbits);
        didx[b * MAXDET + q]   = sbits ? (0xFFFFFFFFu - (unsigned)(key & 0xFFFFFFFFu)) : 0u;
    }
}

// wave per detection (600 blocks -> all rows fetched in parallel): gather row,
// first-occurrence argmax, box -> gbox/glabel
__global__ __launch_bounds__(512) void k_gather(const float* __restrict__ preds,
                                                const float* __restrict__ dscore,
                                                const unsigned* __restrict__ didx,
                                                float* __restrict__ gbox,
                                                int* __restrict__ glabel) {
    int g    = blockIdx.x * 8 + (threadIdx.x >> 6);   // b*MAXDET + k
    int lane = threadIdx.x & 63;
    float sc = dscore[g];
    if (sc > 0.f) {
        int b = g / MAXDET;
        int idx = (int)didx[g];
        const float* row = preds + ((size_t)b * NN + (size_t)idx) * NF;
        float v = row[5 + lane]; int ci = lane;
        if (lane < 16) { float v2 = row[69 + lane]; if (v2 > v) { v = v2; ci = lane + 64; } }
        #pragma unroll
        for (int m = 32; m >= 1; m >>= 1) {
            float ov = __shfl_xor(v, m);
            int   oi = __shfl_xor(ci, m);
            if (ov > v || (ov == v && oi < ci)) { v = ov; ci = oi; }
        }
        if (lane == 0) {
            float cx = row[0], cy = row[1], w = row[2], h = row[3];
            float x1 = cx - 0.5f * w, y1 = cy - 0.5f * h;   // 0.5*w exact -> fma-safe
            float4 bx = { x1, y1, x1 + w, y1 + h };
            ((float4*)gbox)[g] = bx;
            glabel[g] = ci;
        }
    } else if (lane == 0) {
        float4 zz = { 0.f, 0.f, 0.f, 0.f };
        ((float4*)gbox)[g] = zz;
        glabel[g] = -1;
    }
}

// Proven nms2: supp built AND consumed in LDS; boxes->LDS; suppression words
// each written once (jw-rotated loop de-aliases banks); single-wave greedy;
// fused output. IoU op-order matches reference; _rn blocks fma-contract.
__global__ __launch_bounds__(1024) void k_nms2(const float* __restrict__ gbox,
                                               const int* __restrict__ glabel,
                                               const float* __restrict__ dscore,
                                               float* __restrict__ out) {
    __shared__ float4   sbox[MAXDET];
    __shared__ int      slabel[MAXDET];
    __shared__ float    sscore[MAXDET];
    __shared__ unsigned supp[MAXDET * WORDS];
    int b = blockIdx.x;
    int tid = threadIdx.x;

    if (tid < MAXDET) {
        int g = b * MAXDET + tid;
        sbox[tid]   = ((const float4*)gbox)[g];
        slabel[tid] = glabel[g];
        sscore[tid] = dscore[g];
    }
    __syncthreads();

    for (int T = tid; T < MAXDET * WORDS; T += 1024) {
        int i  = T / WORDS;
        int jw = T - i * WORDS;
        unsigned word = 0;
        int jbase = jw * 32;
        if (jbase + 31 > i) {
            float4 bi = sbox[i];
            int   li = slabel[i];
            float si = sscore[i];
            float ai = __fmul_rn(fmaxf(__fsub_rn(bi.z, bi.x), 0.f),
                                 fmaxf(__fsub_rn(bi.w, bi.y), 0.f));
            for (int uu = 0; uu < 32; ++uu) {
                int t = (uu + jw) & 31;       // rotation: neighbors hit different banks
                int j = jbase + t;
                if (j > i && j < MAXDET) {
                    if (slabel[j] == li && si > 0.f && sscore[j] > 0.f) {
                        float4 bj = sbox[j];
                        float xx1 = fmaxf(bi.x, bj.x);
                        float yy1 = fmaxf(bi.y, bj.y);
                        float xx2 = fminf(bi.z, bj.z);
                        float yy2 = fminf(bi.w, bj.w);
                        float iw = fmaxf(__fsub_rn(xx2, xx1), 0.f);
                        float ih = fmaxf(__fsub_rn(yy2, yy1), 0.f);
                        float inter = __fmul_rn(iw, ih);
                        float aj = __fmul_rn(fmaxf(__fsub_rn(bj.z, bj.x), 0.f),
                                             fmaxf(__fsub_rn(bj.w, bj.y), 0.f));
                        float den = __fadd_rn(__fsub_rn(__fadd_rn(ai, aj), inter), 1e-9f);
                        float iou = inter / den;     // exact IEEE div (no fast-math)
                        if (iou > NMSTH) word |= 1u << t;
                    }
                }
            }
        }
        supp[T] = word;
    }
    __syncthreads();

    if (tid < 64) {
        int lane = tid;
        unsigned keep = 0, nzm = 0;
        #pragma unroll
        for (int s = 0; s < 5; ++s) {
            int k = s * 64 + lane;
            bool kb = (k < MAXDET) && (sscore[k] > 0.f);
            unsigned long long m = __ballot(kb);
            if (lane == 2 * s)     keep = (unsigned)m;
            if (lane == 2 * s + 1) keep = (unsigned)(m >> 32);
            unsigned nz = 0;
            if (k < MAXDET) {
                #pragma unroll
                for (int w = 0; w < WORDS; ++w) nz |= supp[k * WORDS + w];
            }
            unsigned long long mn = __ballot(nz != 0u);
            if (lane == 2 * s)     nzm = (unsigned)mn;
            if (lane == 2 * s + 1) nzm = (unsigned)(mn >> 32);
        }

        for (int i = 0; i < MAXDET; ++i) {
            int idx = i >> 5;                       // uniform
            unsigned kw = __shfl(keep, idx);
            unsigned nw = __shfl(nzm, idx);
            if (((kw & nw) >> (i & 31)) & 1u) {
                if (lane < WORDS) keep &= ~supp[i * WORDS + lane];
            }
        }

        #pragma unroll
        for (int s = 0; s < 5; ++s) {
            int k = s * 64 + lane;
            if (k < MAXDET) {
                unsigned kw = __shfl(keep, k >> 5);
                bool kp = (kw >> (k & 31)) & 1u;
                int g = b * MAXDET + k;
                float4 bx = sbox[k];
                float4 zz = { 0.f, 0.f, 0.f, 0.f };
                ((float4*)(out + O_PB))[g] = kp ? bx : zz;
                out[O_PS + g] = kp ? sscore[k] : 0.f;
                out[O_PL + g] = kp ? (float)slabel[k] : -1.f;
                out[O_PV + g] = kp ? 1.f : 0.f;
            }
        }
    }
}

extern "C" void kernel_launch(void* const* d_in, const int* in_sizes, int n_in,
                              void* d_out, int out_size, void* d_ws, size_t ws_size,
                              hipStream_t stream) {
    const float* preds = (const float*)d_in[0];
    const float* tt    = (const float*)d_in[1];
    const int*   len   = (const int*)d_in[2];
    float* out = (float*)d_out;

    char* ws = (char*)d_ws;
    int*      ghist  = (int*)(ws + WS_HIST);
    int*      cnt    = (int*)(ws + WS_CNT);
    unsigned long long* keys = (unsigned long long*)(ws + WS_KEYS);
    float*    dscore = (float*)(ws + WS_DS);
    unsigned* didx   = (unsigned*)(ws + WS_DI);
    float*    gbox   = (float*)(ws + WS_GBOX);
    int*      glabel = (int*)(ws + WS_GLAB);

    k_zero  <<<(BB * NBINS + 1023) / 1024, 1024, 0, stream>>>(ghist, cnt);
    k_score <<<SCORE_BLOCKS + NTGT_BLOCKS, 128, 0, stream>>>(preds, ghist, cnt, keys, tt, len, out);
    k_select<<<BB, 1024, 0, stream>>>(ghist, cnt, keys, dscore, didx);
    k_gather<<<(BB * MAXDET) / 8, 512, 0, stream>>>(preds, dscore, didx, gbox, glabel);
    k_nms2  <<<BB, 1024, 0, stream>>>(gbox, glabel, dscore, out);
}

// Round 15
// 91.714 us; speedup vs baseline: 1.3376x; 1.3376x over previous
//
#include <hip/hip_runtime.h>
#include <cstdint>

#define BB 16
#define NN 25200
#define NCLS 80
#define NF (5 + NCLS)
#define MAXDET 300
#define MTGT 50
#define CONF 0.8f
#define NMSTH 0.4f
#define WORDS 10
#define NBINS 2048
#define SBUF 2048
#define CAPK 8192                           // per-batch candidate list
#define SLICE 1575                          // NN/16: scores per hist/filter block
#define LCAP 1600                           // per-slice survivor cap (~306 expected/batch)
#define APB 64                              // anchors per block in k_score
#define CHUNK_V4 (APB * NF / 4)             // 1360 float4 per block
#define SCORE_BLOCKS ((BB * NN) / APB)      // 6300
#define NTGT_BLOCKS ((BB * MTGT + 127) / 128)
#define HSTRIDE 33                          // hist LDS row stride (bank de-alias)

// workspace byte offsets
#define WS_SCORE 0                                         // 16*25200*4
#define WS_HIST ((size_t)BB * NN * 4)                      // 16*2048*4
#define WS_CNT  (WS_HIST + (size_t)BB * NBINS * 4)         // 16 counters, 64B apart
#define WS_KEYS (WS_CNT + 1024)                            // 16*8192*8
#define WS_DS   (WS_KEYS + (size_t)BB * CAPK * 8)
#define WS_DI   (WS_DS + (size_t)BB * MAXDET * 4)
#define WS_GBOX (WS_DI + (size_t)BB * MAXDET * 4)
#define WS_GLAB (WS_GBOX + (size_t)BB * MAXDET * 16)

// output float offsets (return order: pb, ps, pl, pv, tb, ts, tl, tv)
#define O_PB 0
#define O_PS (BB * MAXDET * 4)
#define O_PL (O_PS + BB * MAXDET)
#define O_PV (O_PL + BB * MAXDET)
#define O_TB (O_PV + BB * MAXDET)
#define O_TS (O_TB + BB * MTGT * 4)
#define O_TL (O_TS + BB * MTGT)
#define O_TV (O_TL + BB * MTGT)

__global__ __launch_bounds__(1024) void k_zero(int* __restrict__ ghist,
                                               int* __restrict__ cnt) {
    int i = blockIdx.x * 1024 + threadIdx.x;
    if (i < BB * NBINS) ghist[i] = 0;
    if (i < 256) cnt[i] = 0;
}

// R12-proven scorer (NO atomics -- R14 lesson): 128-thread block stages 64 rows
// (21.76 KB -> 7 blocks/CU) via async global_load_lds width=16. Scan: 2
// threads/anchor (2-way bank = free), 4 max accumulators (order-independent ->
// bit-exact), one shfl_xor, single f32 mul. Pinned ~22 us = HBM roofline.
__global__ __launch_bounds__(128) void k_score(const float* __restrict__ preds,
                                               float* __restrict__ scores,
                                               const float* __restrict__ tt,
                                               const int* __restrict__ len,
                                               float* __restrict__ out) {
    __shared__ float st[APB * NF];          // 21760 B
    int tid = threadIdx.x;
    int bid = blockIdx.x;

    if (bid >= SCORE_BLOCKS) {              // fused target transform
        int t = (bid - SCORE_BLOCKS) * 128 + tid;
        if (t < BB * MTGT) {
            int b = t / MTGT, m = t - b * MTGT;
            const float* row = tt + (size_t)t * 6;
            bool valid = m < len[b];
            float cx = row[0], cy = row[1], w = row[2], h = row[3];
            float x1 = cx - 0.5f * w, y1 = cy - 0.5f * h;
            float* tb = out + O_TB + (size_t)t * 4;
            tb[0] = valid ? x1 : 0.f;
            tb[1] = valid ? y1 : 0.f;
            tb[2] = valid ? (x1 + w) : 0.f;
            tb[3] = valid ? (y1 + h) : 0.f;
            out[O_TS + t] = valid ? row[4] : 0.f;
            out[O_TL + t] = valid ? (float)(int)row[5] : -1.f;
            out[O_TV + t] = valid ? 1.f : 0.f;
        }
        return;
    }

    int w = tid >> 6;                       // wave id (uniform per wave)
    const float4* src = (const float4*)(preds + (size_t)bid * (APB * NF));
    #pragma unroll
    for (int i = 0; i < 11; ++i) {
        int idx = i * 128 + tid;
        if (idx < CHUNK_V4) {
            __builtin_amdgcn_global_load_lds(
                (const __attribute__((address_space(1))) void*)(src + idx),
                (__attribute__((address_space(3))) void*)(st + (i * 128 + w * 64) * 4),
                16, 0, 0);
        }
    }
    __syncthreads();                        // drains vmcnt -> LDS valid

    int a = tid >> 1, h = tid & 1;          // anchor, half
    const float* cls = st + a * NF + 5 + h * 40;
    float m0 = cls[0], m1 = cls[1], m2 = cls[2], m3 = cls[3];
    #pragma unroll
    for (int f = 4; f < 40; f += 4) {
        m0 = fmaxf(m0, cls[f]);     m1 = fmaxf(m1, cls[f + 1]);
        m2 = fmaxf(m2, cls[f + 2]); m3 = fmaxf(m3, cls[f + 3]);
    }
    float m = fmaxf(fmaxf(m0, m1), fmaxf(m2, m3));
    m = fmaxf(m, __shfl_xor(m, 1));
    if (h == 0) scores[bid * APB + a] = st[a * NF + 4] * m;  // single mul, bit-exact
}

// 256 blocks (16 per batch, 1575 scores each): LDS histogram, merge nonzero
// bins to ghist[b] fire-and-forget (distinct addresses -> no contention).
__global__ __launch_bounds__(1024) void k_hist(const float* __restrict__ scores,
                                               int* __restrict__ ghist) {
    __shared__ int h[NBINS];
    int b = blockIdx.x >> 4, s = blockIdx.x & 15;
    int tid = threadIdx.x;
    for (int i = tid; i < NBINS; i += 1024) h[i] = 0;
    __syncthreads();
    const float* base = scores + (size_t)b * NN + s * SLICE;
    for (int i = tid; i < SLICE; i += 1024) {
        float v = base[i];
        if (v > CONF) {
            unsigned u = __float_as_uint(v);
            int bin = (int)((u - 0x3F400000u) >> 12);
            bin = bin < 0 ? 0 : (bin > NBINS - 1 ? NBINS - 1 : bin);
            atomicAdd(&h[bin], 1);
        }
    }
    __syncthreads();
    for (int i = tid; i < NBINS; i += 1024) {
        int v = h[i];
        if (v) atomicAdd(&ghist[b * NBINS + i], v);   // ~<=300 nonzero per block
    }
}

// 256 blocks: redundant per-block cut-finder (proven wave code) on ghist[b],
// then filter the 1575-score slice; survivors -> LDS list -> ONE counter
// atomic per block -> coalesced global append. Coarse bins only SELECT
// (cut-bin ties all included); exact sort later ORDERS.
__global__ __launch_bounds__(1024) void k_filter(const float* __restrict__ scores,
                                                 const int* __restrict__ ghist,
                                                 int* __restrict__ cnt,
                                                 unsigned long long* __restrict__ keys) {
    __shared__ int hist[64 * HSTRIDE];
    __shared__ unsigned long long sloc[LCAP];
    __shared__ int lc, gbase, scut;
    int b = blockIdx.x >> 4, s = blockIdx.x & 15;
    int tid = threadIdx.x;
    int lane = tid & 63;

    if (tid == 0) lc = 0;
    for (int i = tid; i < NBINS; i += 1024)
        hist[(i >> 5) * HSTRIDE + (i & 31)] = ghist[b * NBINS + i];
    __syncthreads();

    // cut bin: largest bin with suffix-count >= 300 (proven wave scan)
    if (tid < 64) {
        int sb = 0;
        #pragma unroll
        for (int k = 0; k < 32; ++k) sb += hist[lane * HSTRIDE + k];
        int cum = sb;
        #pragma unroll
        for (int d = 1; d < 64; d <<= 1) {
            int o = __shfl_down(cum, d);
            if (lane + d < 64) cum += o;
        }
        unsigned long long m = __ballot(cum >= MAXDET);
        int cutbin = 0;
        if (m) {
            int cutS = 63 - __clzll(m);
            int tail = (cutS < 63) ? __shfl(cum, cutS + 1) : 0;
            int hh = (lane < 32) ? hist[cutS * HSTRIDE + lane] : 0;
            int c2 = hh;
            #pragma unroll
            for (int d = 1; d < 32; d <<= 1) {
                int o = __shfl_down(c2, d);
                if (lane + d < 32) c2 += o;
            }
            c2 += tail;
            unsigned long long m2 = __ballot(lane < 32 && c2 >= MAXDET);
            int cutL = 63 - __clzll(m2);           // m2 != 0 guaranteed
            cutbin = cutS * 32 + cutL;
        }
        if (lane == 0) scut = cutbin;
    }
    __syncthreads();
    int cutbin = scut;

    const float* base = scores + (size_t)b * NN + s * SLICE;
    for (int i = tid; i < SLICE; i += 1024) {
        float v = base[i];
        if (v > CONF) {                                   // explicit CONF guard
            unsigned u = __float_as_uint(v);
            int bin = (int)((u - 0x3F400000u) >> 12);
            bin = bin < 0 ? 0 : (bin > NBINS - 1 ? NBINS - 1 : bin);
            if (bin >= cutbin) {
                int p = atomicAdd(&lc, 1);                // LDS atomic, ~20/block
                if (p < LCAP) {
                    unsigned aidx = (unsigned)(s * SLICE + i);
                    sloc[p] = ((unsigned long long)u << 32) |
                              (unsigned long long)(0xFFFFFFFFu - aidx);
                }
            }
        }
    }
    __syncthreads();
    int n = lc < LCAP ? lc : LCAP;
    if (tid == 0) gbase = atomicAdd(&cnt[b * 16], n);     // ONE return per block
    __syncthreads();
    int gb = gbase;
    for (int i = tid; i < n; i += 1024) {
        int gp = gb + i;
        if (gp < CAPK) keys[(size_t)b * CAPK + gp] = sloc[i];
    }
}

// 16 blocks: ~306 survivor keys -> proven bitonic (P in {512,1024,2048},
// descending) -> dscore/didx. 64-bit key = score bits || inverted index ->
// bit-identical to full sort (JAX top_k tie semantics); append-order
// nondeterminism erased by the total order.
__global__ __launch_bounds__(1024) void k_sel2(const int* __restrict__ cnt,
                                               const unsigned long long* __restrict__ keys,
                                               float* __restrict__ dscore,
                                               unsigned* __restrict__ didx) {
    __shared__ unsigned long long sk[SBUF];
    int b = blockIdx.x;
    int tid = threadIdx.x;
    int M = cnt[b * 16]; if (M > SBUF) M = SBUF;

    for (int i = tid; i < SBUF; i += 1024)
        sk[i] = (i < M) ? keys[(size_t)b * CAPK + i] : 0ull;

    unsigned P = 512;
    while ((int)P < M) P <<= 1;
    for (unsigned k = 2; k <= P; k <<= 1) {
        for (unsigned j = k >> 1; j > 0; j >>= 1) {
            __syncthreads();
            for (unsigned i = tid; i < P; i += 1024) {
                unsigned ixj = i ^ j;
                if (ixj > i) {
                    unsigned long long a = sk[i], d = sk[ixj];
                    bool desc = ((i & k) == 0);
                    if (desc ? (a < d) : (a > d)) { sk[i] = d; sk[ixj] = a; }
                }
            }
        }
    }
    __syncthreads();
    for (int q = tid; q < MAXDET; q += 1024) {
        unsigned long long key = sk[q];
        unsigned sbits = (unsigned)(key >> 32);
        dscore[b * MAXDET + q] = __uint_as_float(sbits);
        didx[b * MAXDET + q]   = sbits ? (0xFFFFFFFFu - (unsigned)(key & 0xFFFFFFFFu)) : 0u;
    }
}

// wave per detection (600 blocks): gather row, first-occurrence argmax, box
__global__ __launch_bounds__(512) void k_gather(const float* __restrict__ preds,
                                                const float* __restrict__ dscore,
                                                const unsigned* __restrict__ didx,
                                                float* __restrict__ gbox,
                                                int* __restrict__ glabel) {
    int g    = blockIdx.x * 8 + (threadIdx.x >> 6);   // b*MAXDET + k
    int lane = threadIdx.x & 63;
    float sc = dscore[g];
    if (sc > 0.f) {
        int b = g / MAXDET;
        int idx = (int)didx[g];
        const float* row = preds + ((size_t)b * NN + (size_t)idx) * NF;
        float v = row[5 + lane]; int ci = lane;
        if (lane < 16) { float v2 = row[69 + lane]; if (v2 > v) { v = v2; ci = lane + 64; } }
        #pragma unroll
        for (int m = 32; m >= 1; m >>= 1) {
            float ov = __shfl_xor(v, m);
            int   oi = __shfl_xor(ci, m);
            if (ov > v || (ov == v && oi < ci)) { v = ov; ci = oi; }
        }
        if (lane == 0) {
            float cx = row[0], cy = row[1], w = row[2], h = row[3];
            float x1 = cx - 0.5f * w, y1 = cy - 0.5f * h;   // fma-safe
            float4 bx = { x1, y1, x1 + w, y1 + h };
            ((float4*)gbox)[g] = bx;
            glabel[g] = ci;
        }
    } else if (lane == 0) {
        float4 zz = { 0.f, 0.f, 0.f, 0.f };
        ((float4*)gbox)[g] = zz;
        glabel[g] = -1;
    }
}

// Proven nms2: supp built AND consumed in LDS; single-wave greedy; fused
// output. IoU op-order matches reference; _rn blocks fma-contract.
__global__ __launch_bounds__(1024) void k_nms2(const float* __restrict__ gbox,
                                               const int* __restrict__ glabel,
                                               const float* __restrict__ dscore,
                                               float* __restrict__ out) {
    __shared__ float4   sbox[MAXDET];
    __shared__ int      slabel[MAXDET];
    __shared__ float    sscore[MAXDET];
    __shared__ unsigned supp[MAXDET * WORDS];
    int b = blockIdx.x;
    int tid = threadIdx.x;

    if (tid < MAXDET) {
        int g = b * MAXDET + tid;
        sbox[tid]   = ((const float4*)gbox)[g];
        slabel[tid] = glabel[g];
        sscore[tid] = dscore[g];
    }
    __syncthreads();

    for (int T = tid; T < MAXDET * WORDS; T += 1024) {
        int i  = T / WORDS;
        int jw = T - i * WORDS;
        unsigned word = 0;
        int jbase = jw * 32;
        if (jbase + 31 > i) {
            float4 bi = sbox[i];
            int   li = slabel[i];
            float si = sscore[i];
            float ai = __fmul_rn(fmaxf(__fsub_rn(bi.z, bi.x), 0.f),
                                 fmaxf(__fsub_rn(bi.w, bi.y), 0.f));
            for (int uu = 0; uu < 32; ++uu) {
                int t = (uu + jw) & 31;       // rotation de-aliases banks
                int j = jbase + t;
                if (j > i && j < MAXDET) {
                    if (slabel[j] == li && si > 0.f && sscore[j] > 0.f) {
                        float4 bj = sbox[j];
                        float xx1 = fmaxf(bi.x, bj.x);
                        float yy1 = fmaxf(bi.y, bj.y);
                        float xx2 = fminf(bi.z, bj.z);
                        float yy2 = fminf(bi.w, bj.w);
                        float iw = fmaxf(__fsub_rn(xx2, xx1), 0.f);
                        float ih = fmaxf(__fsub_rn(yy2, yy1), 0.f);
                        float inter = __fmul_rn(iw, ih);
                        float aj = __fmul_rn(fmaxf(__fsub_rn(bj.z, bj.x), 0.f),
                                             fmaxf(__fsub_rn(bj.w, bj.y), 0.f));
                        float den = __fadd_rn(__fsub_rn(__fadd_rn(ai, aj), inter), 1e-9f);
                        float iou = inter / den;     // exact IEEE div
                        if (iou > NMSTH) word |= 1u << t;
                    }
                }
            }
        }
        supp[T] = word;
    }
    __syncthreads();

    if (tid < 64) {
        int lane = tid;
        unsigned keep = 0, nzm = 0;
        #pragma unroll
        for (int s = 0; s < 5; ++s) {
            int k = s * 64 + lane;
            bool kb = (k < MAXDET) && (sscore[k] > 0.f);
            unsigned long long m = __ballot(kb);
            if (lane == 2 * s)     keep = (unsigned)m;
            if (lane == 2 * s + 1) keep = (unsigned)(m >> 32);
            unsigned nz = 0;
            if (k < MAXDET) {
                #pragma unroll
                for (int w = 0; w < WORDS; ++w) nz |= supp[k * WORDS + w];
            }
            unsigned long long mn = __ballot(nz != 0u);
            if (lane == 2 * s)     nzm = (unsigned)mn;
            if (lane == 2 * s + 1) nzm = (unsigned)(mn >> 32);
        }

        for (int i = 0; i < MAXDET; ++i) {
            int idx = i >> 5;                       // uniform
            unsigned kw = __shfl(keep, idx);
            unsigned nw = __shfl(nzm, idx);
            if (((kw & nw) >> (i & 31)) & 1u) {
                if (lane < WORDS) keep &= ~supp[i * WORDS + lane];
            }
        }

        #pragma unroll
        for (int s = 0; s < 5; ++s) {
            int k = s * 64 + lane;
            if (k < MAXDET) {
                unsigned kw = __shfl(keep, k >> 5);
                bool kp = (kw >> (k & 31)) & 1u;
                int g = b * MAXDET + k;
                float4 bx = sbox[k];
                float4 zz = { 0.f, 0.f, 0.f, 0.f };
                ((float4*)(out + O_PB))[g] = kp ? bx : zz;
                out[O_PS + g] = kp ? sscore[k] : 0.f;
                out[O_PL + g] = kp ? (float)slabel[k] : -1.f;
                out[O_PV + g] = kp ? 1.f : 0.f;
            }
        }
    }
}

extern "C" void kernel_launch(void* const* d_in, const int* in_sizes, int n_in,
                              void* d_out, int out_size, void* d_ws, size_t ws_size,
                              hipStream_t stream) {
    const float* preds = (const float*)d_in[0];
    const float* tt    = (const float*)d_in[1];
    const int*   len   = (const int*)d_in[2];
    float* out = (float*)d_out;

    char* ws = (char*)d_ws;
    float*    scores = (float*)(ws + WS_SCORE);
    int*      ghist  = (int*)(ws + WS_HIST);
    int*      cnt    = (int*)(ws + WS_CNT);
    unsigned long long* keys = (unsigned long long*)(ws + WS_KEYS);
    float*    dscore = (float*)(ws + WS_DS);
    unsigned* didx   = (unsigned*)(ws + WS_DI);
    float*    gbox   = (float*)(ws + WS_GBOX);
    int*      glabel = (int*)(ws + WS_GLAB);

    k_zero  <<<(BB * NBINS + 1023) / 1024, 1024, 0, stream>>>(ghist, cnt);
    k_score <<<SCORE_BLOCKS + NTGT_BLOCKS, 128, 0, stream>>>(preds, scores, tt, len, out);
    k_hist  <<<BB * 16, 1024, 0, stream>>>(scores, ghist);
    k_filter<<<BB * 16, 1024, 0, stream>>>(scores, ghist, cnt, keys);
    k_sel2  <<<BB, 1024, 0, stream>>>(cnt, keys, dscore, didx);
    k_gather<<<(BB * MAXDET) / 8, 512, 0, stream>>>(preds, dscore, didx, gbox, glabel);
    k_nms2  <<<BB, 1024, 0, stream>>>(gbox, glabel, dscore, out);
}

// Round 16
// 88.206 us; speedup vs baseline: 1.3908x; 1.0398x over previous
//
#include <hip/hip_runtime.h>
#include <cstdint>

#define BB 16
#define NN 25200
#define NCLS 80
#define NF (5 + NCLS)
#define MAXDET 300
#define MTGT 50
#define CONF 0.8f
#define NMSTH 0.4f
#define WORDS 10
#define NBINS 2048
#define CAPALL 8192
#define SBUF 2048
#define APB 64
#define CHUNK_V4 (APB * NF / 4)             // 1360
#define SCORE_BLOCKS ((BB * NN) / APB)      // 6300
#define NTGT_BLOCKS ((BB * MTGT + 127) / 128)
#define HSTRIDE 33

// workspace: only the scores array survives
#define WS_SCORE 0

// output float offsets (return order: pb, ps, pl, pv, tb, ts, tl, tv)
#define O_PB 0
#define O_PS (BB * MAXDET * 4)
#define O_PL (O_PS + BB * MAXDET)
#define O_PV (O_PL + BB * MAXDET)
#define O_TB (O_PV + BB * MAXDET)
#define O_TS (O_TB + BB * MTGT * 4)
#define O_TL (O_TS + BB * MTGT)
#define O_TV (O_TL + BB * MTGT)

// Proven scorer: 128-thread block stages 64 rows (21.76 KB -> 7 blocks/CU) via
// async global_load_lds width=16. 2 threads/anchor (2-way bank = free), 4 max
// accumulators (order-independent -> bit-exact), one shfl_xor, single f32 mul.
// ~21 us (R8 subtraction). Tail blocks: target transform.
__global__ __launch_bounds__(128) void k_score(const float* __restrict__ preds,
                                               float* __restrict__ scores,
                                               const float* __restrict__ tt,
                                               const int* __restrict__ len,
                                               float* __restrict__ out) {
    __shared__ float st[APB * NF];          // 21760 B
    int tid = threadIdx.x;
    int bid = blockIdx.x;

    if (bid >= SCORE_BLOCKS) {              // fused target transform
        int t = (bid - SCORE_BLOCKS) * 128 + tid;
        if (t < BB * MTGT) {
            int b = t / MTGT, m = t - b * MTGT;
            const float* row = tt + (size_t)t * 6;
            bool valid = m < len[b];
            float cx = row[0], cy = row[1], w = row[2], h = row[3];
            float x1 = cx - 0.5f * w, y1 = cy - 0.5f * h;
            float* tb = out + O_TB + (size_t)t * 4;
            tb[0] = valid ? x1 : 0.f;
            tb[1] = valid ? y1 : 0.f;
            tb[2] = valid ? (x1 + w) : 0.f;
            tb[3] = valid ? (y1 + h) : 0.f;
            out[O_TS + t] = valid ? row[4] : 0.f;
            out[O_TL + t] = valid ? (float)(int)row[5] : -1.f;
            out[O_TV + t] = valid ? 1.f : 0.f;
        }
        return;
    }

    int w = tid >> 6;                       // wave id (uniform per wave)
    const float4* src = (const float4*)(preds + (size_t)bid * (APB * NF));
    #pragma unroll
    for (int i = 0; i < 11; ++i) {
        int idx = i * 128 + tid;
        if (idx < CHUNK_V4) {
            __builtin_amdgcn_global_load_lds(
                (const __attribute__((address_space(1))) void*)(src + idx),
                (__attribute__((address_space(3))) void*)(st + (i * 128 + w * 64) * 4),
                16, 0, 0);
        }
    }
    __syncthreads();                        // drains vmcnt -> LDS valid

    int a = tid >> 1, h = tid & 1;          // anchor, half
    const float* cls = st + a * NF + 5 + h * 40;
    float m0 = cls[0], m1 = cls[1], m2 = cls[2], m3 = cls[3];
    #pragma unroll
    for (int f = 4; f < 40; f += 4) {
        m0 = fmaxf(m0, cls[f]);     m1 = fmaxf(m1, cls[f + 1]);
        m2 = fmaxf(m2, cls[f + 2]); m3 = fmaxf(m3, cls[f + 3]);
    }
    float m = fmaxf(fmaxf(m0, m1), fmaxf(m2, m3));
    m = fmaxf(m, __shfl_xor(m, 1));
    if (h == 0) scores[bid * APB + a] = st[a * NF + 4] * m;  // single mul, bit-exact
}

// Fully-fused post (16 blocks x 1024): R8's fusion rebuilt from the proven fast
// phases. A: float4 single-pass hist + compact-all (R12). B: wave cut-finder.
// C: LDS filter. D: bitonic-512. E: thread-pair gather (2 thr/det, 40 unrolled
// independent loads each -- replaces R8's serial wave-gather). F: jw-rotated
// suppression words. G: single-wave greedy + output. Coarse bins only SELECT
// (cut-bin ties all included); exact 64-bit key sort ORDERS -> bit-identical
// to full sort (JAX top_k tie semantics via inverted index).
__global__ __launch_bounds__(1024) void k_post(const float* __restrict__ scores,
                                               const float* __restrict__ preds,
                                               float* __restrict__ out) {
    __shared__ unsigned long long skall[CAPALL];  // 65536 B
    __shared__ unsigned long long sk[SBUF];       // 16384 B
    __shared__ int hist[64 * HSTRIDE];            // 8448 B
    __shared__ float4   sbox[MAXDET];
    __shared__ int      slabel[MAXDET];
    __shared__ float    sscore[MAXDET];
    __shared__ unsigned supp[MAXDET * WORDS];     // total ~110 KB
    __shared__ int lcnt, lcnt2, scut;
    int b = blockIdx.x;
    int tid = threadIdx.x;
    int lane = tid & 63;

    if (tid == 0) { lcnt = 0; lcnt2 = 0; }
    for (int i = tid; i < 64 * HSTRIDE; i += 1024) hist[i] = 0;
    for (int i = tid; i < SBUF; i += 1024) sk[i] = 0ull;   // pad keys for sort
    __syncthreads();

    // phase A: one float4 pass: hist + compact-all (>CONF). scores in (0.8,1.0]
    // share one exponent region -> (u-0x3F400000)>>12 monotone in float order.
    const float4* src4 = (const float4*)(scores + (size_t)b * NN);
    for (int v = tid; v < 7168; v += 1024) {            // NN/4 = 6300
        float4 s4 = make_float4(0.f, 0.f, 0.f, 0.f);
        if (v < NN / 4) s4 = src4[v];
        #pragma unroll
        for (int c = 0; c < 4; ++c) {
            float s = (c == 0) ? s4.x : (c == 1) ? s4.y : (c == 2) ? s4.z : s4.w;
            bool pass = s > CONF;
            unsigned u = __float_as_uint(s);
            if (pass) {
                int bin = (int)((u - 0x3F400000u) >> 12);
                bin = bin < 0 ? 0 : (bin > NBINS - 1 ? NBINS - 1 : bin);
                atomicAdd(&hist[(bin >> 5) * HSTRIDE + (bin & 31)], 1);
            }
            unsigned long long mask = __ballot(pass);
            int wcnt = __popcll(mask);
            int bs = 0;
            if (lane == 0 && wcnt) bs = atomicAdd(&lcnt, wcnt);
            bs = __shfl(bs, 0);
            if (pass) {
                int pos = bs + __popcll(mask & ((1ull << lane) - 1ull));
                if (pos < CAPALL)
                    skall[pos] = ((unsigned long long)u << 32) |
                                 (unsigned long long)(0xFFFFFFFFu - (unsigned)(4 * v + c));
            }
        }
    }
    __syncthreads();

    // phase B: cut bin (largest bin with suffix-count >= 300), one wave
    if (tid < 64) {
        int sb = 0;
        #pragma unroll
        for (int k = 0; k < 32; ++k) sb += hist[lane * HSTRIDE + k];
        int cum = sb;
        #pragma unroll
        for (int d = 1; d < 64; d <<= 1) {
            int o = __shfl_down(cum, d);
            if (lane + d < 64) cum += o;
        }
        unsigned long long m = __ballot(cum >= MAXDET);
        int cutbin = 0;
        if (m) {
            int cutS = 63 - __clzll(m);
            int tail = (cutS < 63) ? __shfl(cum, cutS + 1) : 0;
            int hh = (lane < 32) ? hist[cutS * HSTRIDE + lane] : 0;
            int c2 = hh;
            #pragma unroll
            for (int d = 1; d < 32; d <<= 1) {
                int o = __shfl_down(c2, d);
                if (lane + d < 32) c2 += o;
            }
            c2 += tail;
            unsigned long long m2 = __ballot(lane < 32 && c2 >= MAXDET);
            int cutL = 63 - __clzll(m2);           // m2 != 0 guaranteed
            cutbin = cutS * 32 + cutL;
        }
        if (lane == 0) scut = cutbin;
    }
    __syncthreads();
    int cutbin = scut;

    // phase C: filter skall by bin >= cutbin (wave-aggregated, LDS-only reads)
    int M = lcnt; if (M > CAPALL) M = CAPALL;
    for (int i = tid; i < ((M + 1023) & ~1023); i += 1024) {
        bool pass = false;
        unsigned long long key = 0ull;
        if (i < M) {
            key = skall[i];
            unsigned u = (unsigned)(key >> 32);
            int bin = (int)((u - 0x3F400000u) >> 12);
            bin = bin < 0 ? 0 : (bin > NBINS - 1 ? NBINS - 1 : bin);
            pass = bin >= cutbin;
        }
        unsigned long long mask = __ballot(pass);
        int wcnt = __popcll(mask);
        int bs = 0;
        if (lane == 0 && wcnt) bs = atomicAdd(&lcnt2, wcnt);
        bs = __shfl(bs, 0);
        if (pass) {
            int pos = bs + __popcll(mask & ((1ull << lane) - 1ull));
            if (pos < SBUF) sk[pos] = key;
        }
    }
    __syncthreads();

    // phase D: bitonic sort P in {512,1024,2048}, descending (proven)
    int M2 = lcnt2; if (M2 > SBUF) M2 = SBUF;
    unsigned P = 512;
    while ((int)P < M2) P <<= 1;
    for (unsigned k = 2; k <= P; k <<= 1) {
        for (unsigned j = k >> 1; j > 0; j >>= 1) {
            __syncthreads();
            for (unsigned i = tid; i < P; i += 1024) {
                unsigned ixj = i ^ j;
                if (ixj > i) {
                    unsigned long long a = sk[i], d = sk[ixj];
                    bool desc = ((i & k) == 0);
                    if (desc ? (a < d) : (a > d)) { sk[i] = d; sk[ixj] = a; }
                }
            }
        }
    }
    __syncthreads();

    // phase E: thread-pair gather. det k = tid>>1, half h = tid&1: each thread
    // scans 40 classes (independent unrolled loads -> MLP), strict > keeps
    // first occurrence within half; shfl_xor(1) combine prefers lower class on
    // tie -> identical semantics to the proven wave argmax.
    {
        int k = tid >> 1, h = tid & 1;
        if (k < MAXDET) {
            unsigned long long key = sk[k];
            unsigned sbits = (unsigned)(key >> 32);
            if (sbits) {
                int idx = (int)(0xFFFFFFFFu - (unsigned)(key & 0xFFFFFFFFu));
                const float* row = preds + ((size_t)b * NN + (size_t)idx) * NF;
                const float* cls = row + 5 + h * 40;
                float v = cls[0]; int ci = h * 40;
                #pragma unroll
                for (int f = 1; f < 40; ++f) {
                    float x = cls[f];
                    if (x > v) { v = x; ci = h * 40 + f; }
                }
                float ov = __shfl_xor(v, 1);
                int   oi = __shfl_xor(ci, 1);
                if (ov > v || (ov == v && oi < ci)) { v = ov; ci = oi; }
                if (h == 0) {
                    float cx = row[0], cy = row[1], w = row[2], hh = row[3];
                    float x1 = cx - 0.5f * w, y1 = cy - 0.5f * hh;  // fma-safe
                    float4 bx = { x1, y1, x1 + w, y1 + hh };
                    sbox[k] = bx;
                    slabel[k] = ci;
                    sscore[k] = __uint_as_float(sbits);
                }
            } else if (h == 0) {
                float4 zz = { 0.f, 0.f, 0.f, 0.f };
                sbox[k] = zz; slabel[k] = -1; sscore[k] = 0.f;
            }
        }
    }
    __syncthreads();

    // phase F: suppression words (thread per word, jw-rotated inner loop
    // de-aliases banks, no atomics). IoU op-order = reference; _rn blocks
    // fma-contract; exact IEEE div.
    for (int T = tid; T < MAXDET * WORDS; T += 1024) {
        int i  = T / WORDS;
        int jw = T - i * WORDS;
        unsigned word = 0;
        int jbase = jw * 32;
        if (jbase + 31 > i) {
            float4 bi = sbox[i];
            int   li = slabel[i];
            float si = sscore[i];
            float ai = __fmul_rn(fmaxf(__fsub_rn(bi.z, bi.x), 0.f),
                                 fmaxf(__fsub_rn(bi.w, bi.y), 0.f));
            for (int uu = 0; uu < 32; ++uu) {
                int t = (uu + jw) & 31;
                int j = jbase + t;
                if (j > i && j < MAXDET) {
                    if (slabel[j] == li && si > 0.f && sscore[j] > 0.f) {
                        float4 bj = sbox[j];
                        float xx1 = fmaxf(bi.x, bj.x);
                        float yy1 = fmaxf(bi.y, bj.y);
                        float xx2 = fminf(bi.z, bj.z);
                        float yy2 = fminf(bi.w, bj.w);
                        float iw = fmaxf(__fsub_rn(xx2, xx1), 0.f);
                        float ih = fmaxf(__fsub_rn(yy2, yy1), 0.f);
                        float inter = __fmul_rn(iw, ih);
                        float aj = __fmul_rn(fmaxf(__fsub_rn(bj.z, bj.x), 0.f),
                                             fmaxf(__fsub_rn(bj.w, bj.y), 0.f));
                        float den = __fadd_rn(__fsub_rn(__fadd_rn(ai, aj), inter), 1e-9f);
                        float iou = inter / den;
                        if (iou > NMSTH) word |= 1u << t;
                    }
                }
            }
        }
        supp[T] = word;
    }
    __syncthreads();

    // phase G: single-wave greedy (registers + ballot, LDS only on real
    // suppressions) + fused output write with reference masking.
    if (tid < 64) {
        unsigned keep = 0, nzm = 0;
        #pragma unroll
        for (int s = 0; s < 5; ++s) {
            int k = s * 64 + lane;
            bool kb = (k < MAXDET) && (sscore[k] > 0.f);
            unsigned long long m = __ballot(kb);
            if (lane == 2 * s)     keep = (unsigned)m;
            if (lane == 2 * s + 1) keep = (unsigned)(m >> 32);
            unsigned nz = 0;
            if (k < MAXDET) {
                #pragma unroll
                for (int w = 0; w < WORDS; ++w) nz |= supp[k * WORDS + w];
            }
            unsigned long long mn = __ballot(nz != 0u);
            if (lane == 2 * s)     nzm = (unsigned)mn;
            if (lane == 2 * s + 1) nzm = (unsigned)(mn >> 32);
        }

        for (int i = 0; i < MAXDET; ++i) {
            int idx = i >> 5;                       // uniform
            unsigned kw = __shfl(keep, idx);
            unsigned nw = __shfl(nzm, idx);
            if (((kw & nw) >> (i & 31)) & 1u) {
                if (lane < WORDS) keep &= ~supp[i * WORDS + lane];
            }
        }

        #pragma unroll
        for (int s = 0; s < 5; ++s) {
            int k = s * 64 + lane;
            if (k < MAXDET) {
                unsigned kw = __shfl(keep, k >> 5);
                bool kp = (kw >> (k & 31)) & 1u;
                int g = b * MAXDET + k;
                float4 bx = sbox[k];
                float4 zz = { 0.f, 0.f, 0.f, 0.f };
                ((float4*)(out + O_PB))[g] = kp ? bx : zz;
                out[O_PS + g] = kp ? sscore[k] : 0.f;
                out[O_PL + g] = kp ? (float)slabel[k] : -1.f;
                out[O_PV + g] = kp ? 1.f : 0.f;
            }
        }
    }
}

extern "C" void kernel_launch(void* const* d_in, const int* in_sizes, int n_in,
                              void* d_out, int out_size, void* d_ws, size_t ws_size,
                              hipStream_t stream) {
    const float* preds = (const float*)d_in[0];
    const float* tt    = (const float*)d_in[1];
    const int*   len   = (const int*)d_in[2];
    float* out = (float*)d_out;

    float* scores = (float*)((char*)d_ws + WS_SCORE);

    k_score<<<SCORE_BLOCKS + NTGT_BLOCKS, 128, 0, stream>>>(preds, scores, tt, len, out);
    k_post <<<BB, 1024, 0, stream>>>(scores, preds, out);
}